// Round 1
// 111.133 us; speedup vs baseline: 1.0188x; 1.0188x over previous
//
#include <hip/hip_runtime.h>

// GuidedFilterLayer: out = x*(1-eps) + eps*(2*smoothed - 1)
//   g        = luma((x+1)/2)
//   smoothed = boxblur15_zeropad(g + offset),  offset = mean(inputs)-mean(g)
// Linearity: boxblur_zeropad(g + c) = boxblur_zeropad(g) + c*cx(x)*cy(y)/225,
// so offset only enters the final combine. History: R3 removed 8192 contended
// atomics (232->128us); R6 rolling-sum vblur (128->119us); R7: fp16 tmp,
// rolling hblur, k_reduce folded into K2 (112-113us; ~65us of dur_us is
// harness poison/restore traffic, kernels ~50us vs ~27-30us traffic floor).
// This round (R8):
//  * K1 hblur read pattern was ds_read_b32 at 16B lane stride -> 8-way bank
//    conflict on all 21 taps (~357 cyc/wave LDS serialization, ~9.5us/CU).
//    Replaced with 5 aligned ds_read_b128 (conflict-free, ~60 cyc/wave);
//    window [c0..c0+19] = 5 float4s, same adds in registers.
//  * exact offset: K1 writes 4096 partials (grid is 4096 blocks) but old K2
//    reduced only 2048 (benign: offset term ~1e-5). Now reduces all 4096.
//  * K2: two 8-row strips per 256-thread block (512 blocks) to halve the
//    total partials-head work; occupancy unchanged at 8 waves/CU.
//  * luma folded onto raw x: l = 0.5*dot(W,x)+0.5*sum(W), sI = 0.5*sum(x)+6.
// Shapes fixed by the reference: x [16,512,512,3] fp32 NHWC.

#define BATCH  16
#define HEIGHT 512
#define WIDTH  512
#define NPIX   (BATCH * HEIGHT * WIDTH)   // 4,194,304
#define RAD    7
#define KS     15
#define EPSV   0.01f

#define W_R 0.2989f
#define W_G 0.5870f
#define W_B 0.1140f
#define WSUM (W_R + W_G + W_B)            // 0.9999

typedef _Float16 h4 __attribute__((ext_vector_type(4)));

// ---------------- K1: luma + rolling horizontal 15-tap + per-block partials -----------
// Block = 2 rows (1024 px), 256 threads; thread t owns pixels 4t..4t+3
// (= float4s 3t..3t+2, directly loaded). Luma into an aligned-pad LDS row
// ([8 pad][512][8 pad]), one barrier, then hblur via 5 conflict-free
// ds_read_b128 covering padded cols [c0..c0+19]. tmp stored as fp16x4.
__global__ __launch_bounds__(256) void k_luma_hblur(const float* __restrict__ x,
                                                    h4* __restrict__ tmp,
                                                    float2* __restrict__ partials) {
    __shared__ float sl[2][528];            // [8 zero][512 luma][8 zero]
    __shared__ float redG[4], redI[4];
    int t  = threadIdx.x;
    int lr = t >> 7;                        // local row 0/1
    int tc = t & 127;                       // float4-column within row
    int c0 = tc << 2;                       // first pixel column

    if (t < 8) {                            // zero halos once (pre-barrier)
        sl[0][t] = 0.f; sl[1][t] = 0.f;
        sl[0][520 + t] = 0.f; sl[1][520 + t] = 0.f;
    }

    const float4* xv = (const float4*)x;
    size_t tb = (size_t)blockIdx.x * 768 + 3 * t;
    float4 A = xv[tb + 0];
    float4 B = xv[tb + 1];
    float4 C = xv[tb + 2];

    // luma directly on raw x: luma((x+1)/2) = 0.5*dot(W,x) + 0.5*sum(W)
    float d0 = W_R * A.x + W_G * A.y + W_B * A.z;
    float d1 = W_R * A.w + W_G * B.x + W_B * B.y;
    float d2 = W_R * B.z + W_G * B.w + W_B * C.x;
    float d3 = W_R * C.y + W_G * C.z + W_B * C.w;
    float l0 = 0.5f * d0 + (0.5f * WSUM);
    float l1 = 0.5f * d1 + (0.5f * WSUM);
    float l2 = 0.5f * d2 + (0.5f * WSUM);
    float l3 = 0.5f * d3 + (0.5f * WSUM);

    *(float4*)&sl[lr][8 + c0] = make_float4(l0, l1, l2, l3);   // 16B-aligned b128

    float sG = (l0 + l1) + (l2 + l3);
    // sum of 12 mapped inputs = 0.5*sum(raw) + 12*0.5
    float sx = ((A.x + A.y) + (A.z + A.w))
             + ((B.x + B.y) + (B.z + B.w))
             + ((C.x + C.y) + (C.z + C.w));
    float sI = 0.5f * sx + 6.0f;
#pragma unroll
    for (int off = 32; off > 0; off >>= 1) {
        sG += __shfl_down(sG, off, 64);
        sI += __shfl_down(sI, off, 64);
    }
    int lane = t & 63, wave = t >> 6;
    if (lane == 0) { redG[wave] = sG; redI[wave] = sI; }
    __syncthreads();                        // covers sl + redG/redI

    if (t == 0)
        partials[blockIdx.x] = make_float2(redG[0] + redG[1] + redG[2] + redG[3],
                                           redI[0] + redI[1] + redI[2] + redI[3]);

    // hblur: output col c needs padded slots [c+1 .. c+15]; for c0..c0+3 the
    // union is [c0+1 .. c0+18], read as 5 aligned float4s [c0 .. c0+19].
    // Lane byte-stride is 16B -> conflict-free b128 pattern.
    const float4* rowv = (const float4*)&sl[lr][c0];
    float4 p0 = rowv[0];
    float4 p1 = rowv[1];
    float4 p2 = rowv[2];
    float4 p3 = rowv[3];
    float4 p4 = rowv[4];

    float s1_3   = (p0.y + p0.z) + p0.w;
    float s4_7   = (p1.x + p1.y) + (p1.z + p1.w);
    float s8_11  = (p2.x + p2.y) + (p2.z + p2.w);
    float s12_15 = (p3.x + p3.y) + (p3.z + p3.w);
    float o0 = (s1_3 + s4_7) + (s8_11 + s12_15);   // slots c0+1..c0+15
    float o1 = o0 + p4.x - p0.y;                   // +c0+16 -c0+1
    float o2 = o1 + p4.y - p0.z;
    float o3 = o2 + p4.z - p0.w;

    h4 hv; hv.x = (_Float16)o0; hv.y = (_Float16)o1; hv.z = (_Float16)o2; hv.w = (_Float16)o3;
    tmp[(size_t)(blockIdx.x * 2 + lr) * 128 + tc] = hv;   // 1/225 folded into K2
}

// ---------------- K2: inline offset-reduce + rolling vblur + fused combine ------------
// Block = 256 threads = two independent 8-row strips (half = t>>7); thread
// owns float4 column tc = t&127. 512 blocks = 2 blocks/CU = 8 waves/CU.
// First re-reduce ALL 4096 partials (32KB, L2/L3-resident), then vertical
// rolling sum with 2 fp16x4 tap loads per row; combine is pure registers.
#define TROWS 8
__global__ __launch_bounds__(256) void k_vblur_combine(const h4* __restrict__ tmp,
                                                       const float* __restrict__ x,
                                                       float* __restrict__ out,
                                                       const float2* __restrict__ partials) {
    __shared__ float rr[8];
    int t = threadIdx.x;

    // ---- offset = mean(inputs) - mean(g), reduced per-block (exact: 4096) ----
    float sG = 0.f, sI = 0.f;
#pragma unroll
    for (int i = 0; i < 16; i++) {
        float2 v = partials[t + (i << 8)];
        sG += v.x; sI += v.y;
    }
#pragma unroll
    for (int off = 32; off > 0; off >>= 1) {
        sG += __shfl_down(sG, off, 64);
        sI += __shfl_down(sI, off, 64);
    }
    int lane = t & 63, wave = t >> 6;
    if (lane == 0) { rr[wave] = sG; rr[4 + wave] = sI; }
    __syncthreads();
    float offset = (rr[4] + rr[5] + rr[6] + rr[7]) * (1.f / (3.f * (float)NPIX))
                 - (rr[0] + rr[1] + rr[2] + rr[3]) * (1.f / (float)NPIX);

    int half = t >> 7;                      // which 8-row strip
    int tc   = t & 127;
    int band = blockIdx.x & 31;             // 32 bands of 16 rows per image
    int b    = blockIdx.x >> 5;
    int y0   = band * 16 + half * TROWS;
    const float nrm   = 1.f / (float)(KS * KS);
    const float scale = 1.f - EPSV;

    int col = tc << 2;
    float c0 = (float)(min(col + 0, RAD) + 1 + min(WIDTH - 1 - col, RAD));
    float c1 = (float)(min(col + 1, RAD) + 1 + min(WIDTH - 2 - col, RAD));
    float c2 = (float)(min(col + 2, RAD) + 1 + min(WIDTH - 3 - col, RAD));
    float c3 = (float)(min(col + 3, RAD) + 1 + min(WIDTH - 4 - col, RAD));

    const h4* tv = tmp + (size_t)b * HEIGHT * 128 + tc;

    // init window = rows [max(0,y0-7), y0+7]
    float s0 = 0.f, s1 = 0.f, s2 = 0.f, s3 = 0.f;
    int rlo = y0 - RAD < 0 ? 0 : y0 - RAD;
    for (int r = rlo; r <= y0 + RAD; ++r) {
        h4 v = tv[(size_t)r * 128];
        s0 += (float)v.x; s1 += (float)v.y; s2 += (float)v.z; s3 += (float)v.w;
    }

    const float4* xv = (const float4*)x + (size_t)b * HEIGHT * 384;
    float4*       ov = (float4*)out     + (size_t)b * HEIGHT * 384;

#pragma unroll
    for (int i = 0; i < TROWS; ++i) {
        int y = y0 + i;
        float cy = (float)(min(y, RAD) + 1 + min(HEIGHT - 1 - y, RAD));
        float k  = offset * cy;
        float a0 = EPSV * (2.f * (s0 + k * c0) * nrm - 1.f);
        float a1 = EPSV * (2.f * (s1 + k * c1) * nrm - 1.f);
        float a2 = EPSV * (2.f * (s2 + k * c2) * nrm - 1.f);
        float a3 = EPSV * (2.f * (s3 + k * c3) * nrm - 1.f);

        size_t rb = (size_t)y * 384 + 3 * tc;
        float4 x0 = xv[rb + 0];
        float4 x1 = xv[rb + 1];
        float4 x2 = xv[rb + 2];
        float4 o0, o1, o2;
        o0.x = x0.x * scale + a0; o0.y = x0.y * scale + a0;
        o0.z = x0.z * scale + a0; o0.w = x0.w * scale + a1;
        o1.x = x1.x * scale + a1; o1.y = x1.y * scale + a1;
        o1.z = x1.z * scale + a2; o1.w = x1.w * scale + a2;
        o2.x = x2.x * scale + a2; o2.y = x2.y * scale + a3;
        o2.z = x2.z * scale + a3; o2.w = x2.w * scale + a3;
        ov[rb + 0] = o0;
        ov[rb + 1] = o1;
        ov[rb + 2] = o2;

        if (y + RAD + 1 < HEIGHT) {         // wave-uniform (half is per-wave const)
            h4 v = tv[(size_t)(y + RAD + 1) * 128];
            s0 += (float)v.x; s1 += (float)v.y; s2 += (float)v.z; s3 += (float)v.w;
        }
        if (y - RAD >= 0) {
            h4 v = tv[(size_t)(y - RAD) * 128];
            s0 -= (float)v.x; s1 -= (float)v.y; s2 -= (float)v.z; s3 -= (float)v.w;
        }
    }
}

extern "C" void kernel_launch(void* const* d_in, const int* in_sizes, int n_in,
                              void* d_out, int out_size, void* d_ws, size_t ws_size,
                              hipStream_t stream) {
    const float* x   = (const float*)d_in[0];
    float*       out = (float*)d_out;

    // ws layout: [0, 32K): partials (4096 float2) | [32K, 32K+8.4M): tmp fp16
    float2* partials = (float2*)d_ws;
    h4*     tmp      = (h4*)((char*)d_ws + 32768);

    k_luma_hblur<<<BATCH * HEIGHT / 2, 256, 0, stream>>>(x, tmp, partials);
    k_vblur_combine<<<BATCH * (HEIGHT / 16), 256, 0, stream>>>(tmp, x, out, partials);
}